// Round 13
// baseline (273.579 us; speedup 1.0000x reference)
//
#include <hip/hip_runtime.h>
#include <hip/hip_bf16.h>
#include <math.h>

#define HW   65536   // 256*256
#define NPIX 524288  // 8*65536
#define NB   8
#define NT   6
#define NC   48      // nt*nb combined channels
#define DIM  64
#define EE   128
#define KSTEPS 14    // K = 9 taps * 48 ch = 432, padded to 448 = 14 * 32
#define KVALID 432
#define COLS 130

typedef short bf16x8 __attribute__((ext_vector_type(8)));
typedef float f32x4  __attribute__((ext_vector_type(4)));

__device__ __forceinline__ float gelu_exact(float v) {
    return 0.5f * v * (1.0f + erff(v * 0.70710678118654752f));
}

__device__ __forceinline__ unsigned pack_bf16(float v0, float v1) {
    __hip_bfloat16 h0 = __float2bfloat16(v0);
    __hip_bfloat16 h1 = __float2bfloat16(v1);
    return (unsigned)(*(unsigned short*)&h0) | ((unsigned)(*(unsigned short*)&h1) << 16);
}

// ---------------- Kernel A: fold prompt into conv weights, fragment-ordered bf16 ----
__global__ __launch_bounds__(256) void fold_weights_kernel(
    const float* __restrict__ conv_w,   // [128][128][3][3]
    const float* __restrict__ prompt,   // [6][8][128]
    unsigned short* __restrict__ WfB)   // [14][8][64][8] bf16
{
    int f = blockIdx.x * 256 + threadIdx.x;   // 0 .. 57343
    int j    = f & 7;
    int lane = (f >> 3) & 63;
    int ob   = (f >> 9) & 7;
    int ks   = f >> 12;

    int o = ob * 16 + (lane & 15);
    int k = ks * 32 + ((lane >> 4) << 3) + j;

    float acc = 0.f;
    if (k < KVALID) {
        int tap = k / 48;
        int tk  = k - tap * 48;
        int dy = tap / 3;
        int dx = tap - dy * 3;
        const float* pw = conv_w + ((size_t)o * EE) * 9 + dy * 3 + dx;
        const float* pp = prompt + (size_t)tk * EE;
        #pragma unroll 4
        for (int e = 0; e < EE; ++e)
            acc += pw[(size_t)e * 9] * pp[e];
    }
    __hip_bfloat16 h = __float2bfloat16(acc);
    WfB[f] = *(unsigned short*)&h;
}

// ---------------- Kernel B1: flux MLP1 -> t-logit planes [6][NPIX] ----
// 4 px/thread, float4 loads (16B/lane), single-MLP state: ~70 VGPR clean.
__global__ __launch_bounds__(128) void flux_mlp_kernel(
    const float* __restrict__ flux,   // [8][128][256][256]
    const float* __restrict__ t1w, const float* __restrict__ t1b,
    float* __restrict__ traw)         // [6][NPIX]
{
    __shared__ float s_t1w[EE * 8];   // [ci][j] transposed, j<6 padded 0
    __shared__ float s_t1b[8];

    int tid = threadIdx.x;
    for (int i = tid; i < EE * 8; i += 128) {
        int ci = i >> 3, j = i & 7;
        s_t1w[i] = (j < NT) ? t1w[j * EE + ci] : 0.f;
    }
    if (tid < 8) s_t1b[tid] = (tid < NT) ? t1b[tid] : 0.f;
    __syncthreads();

    int gq   = blockIdx.x * 128 + tid;   // 0..131071
    int pix0 = gq << 2;
    int b    = pix0 >> 16;
    int yx   = pix0 & (HW - 1);
    const float* fp = flux + (size_t)b * EE * HW + yx;

    float t[4][6];
    #pragma unroll
    for (int p = 0; p < 4; ++p)
        #pragma unroll
        for (int j = 0; j < NT; ++j) t[p][j] = s_t1b[j];

    #pragma unroll 1
    for (int cb = 0; cb < EE; cb += 8) {
        float4 v[8];
        #pragma unroll
        for (int u = 0; u < 8; ++u)
            v[u] = *(const float4*)(fp + (size_t)(cb + u) * HW);
        #pragma unroll
        for (int u = 0; u < 8; ++u) {
            const float* wp = &s_t1w[(cb + u) * 8];
            float4 wA = *(const float4*)wp;
            float2 wB = *(const float2*)(wp + 4);
            float pv[4] = {v[u].x, v[u].y, v[u].z, v[u].w};
            #pragma unroll
            for (int p = 0; p < 4; ++p) {
                float f = pv[p];
                f = (f == f) ? f : 0.f;
                t[p][0] += f * wA.x;
                t[p][1] += f * wA.y;
                t[p][2] += f * wA.z;
                t[p][3] += f * wA.w;
                t[p][4] += f * wB.x;
                t[p][5] += f * wB.y;
            }
        }
    }

    // contiguous float4 stores per plane (1KB/wave-instr)
    #pragma unroll
    for (int j = 0; j < NT; ++j) {
        float4 q = make_float4(t[0][j], t[1][j], t[2][j], t[3][j]);
        *(float4*)&traw[(size_t)j * NPIX + pix0] = q;
    }
}

// ---------------- Kernel B2: x MLP1 + both softmaxes + outer -> c2 ----
// 4 px/thread, float4 loads; a[4][8] + staging ~78 VGPR clean.
__global__ __launch_bounds__(128) void basis_epilogue_kernel(
    const float* __restrict__ x,      // [8][64][256][256]
    const float* __restrict__ traw,   // [6][NPIX]
    const float* __restrict__ b1w, const float* __restrict__ b1b,
    const float* __restrict__ b2w, const float* __restrict__ b2b,
    const float* __restrict__ t2w, const float* __restrict__ t2b,
    uint4* __restrict__ c2)           // [6][NPIX]
{
    __shared__ float s_b1w[DIM * 8];
    __shared__ float s_b2w[64];
    __shared__ float s_t2w[36];
    __shared__ float s_b1b[8], s_b2b[8], s_t2b[8];

    int tid = threadIdx.x;
    for (int i = tid; i < DIM * 8; i += 128) {
        int ci = i >> 3, j = i & 7;
        s_b1w[i] = b1w[j * DIM + ci];
    }
    if (tid < 64) s_b2w[tid] = b2w[tid];
    if (tid < 36) s_t2w[tid] = t2w[tid];
    if (tid < 8) {
        s_b1b[tid] = b1b[tid];
        s_b2b[tid] = b2b[tid];
        s_t2b[tid] = (tid < NT) ? t2b[tid] : 0.f;
    }
    __syncthreads();

    int gq   = blockIdx.x * 128 + tid;   // 0..131071
    int pix0 = gq << 2;
    int b    = pix0 >> 16;
    int yx   = pix0 & (HW - 1);
    const float* xp = x + (size_t)b * DIM * HW + yx;

    float a[4][8];
    #pragma unroll
    for (int p = 0; p < 4; ++p)
        #pragma unroll
        for (int j = 0; j < 8; ++j) a[p][j] = s_b1b[j];

    #pragma unroll 1
    for (int cb = 0; cb < DIM; cb += 8) {
        float4 v[8];
        #pragma unroll
        for (int u = 0; u < 8; ++u)
            v[u] = *(const float4*)(xp + (size_t)(cb + u) * HW);
        #pragma unroll
        for (int u = 0; u < 8; ++u) {
            const float* wp = &s_b1w[(cb + u) * 8];
            float4 wa = *(const float4*)wp;
            float4 wb = *(const float4*)(wp + 4);
            float pv[4] = {v[u].x, v[u].y, v[u].z, v[u].w};
            #pragma unroll
            for (int p = 0; p < 4; ++p) {
                float f = pv[p];
                a[p][0] += f * wa.x;
                a[p][1] += f * wa.y;
                a[p][2] += f * wa.z;
                a[p][3] += f * wa.w;
                a[p][4] += f * wb.x;
                a[p][5] += f * wb.y;
                a[p][6] += f * wb.z;
                a[p][7] += f * wb.w;
            }
        }
    }

    // coalesced t-logit loads: 6 planes x float4 (4 pixels)
    float4 tj[6];
    #pragma unroll
    for (int j = 0; j < NT; ++j)
        tj[j] = *(const float4*)&traw[(size_t)j * NPIX + pix0];

    #pragma unroll
    for (int p = 0; p < 4; ++p) {
        // task = softmax6(fc2(gelu(t[p])))  (p static after unroll -> ternary folds)
        float task[6];
        {
            float gt[6];
            #pragma unroll
            for (int j = 0; j < NT; ++j) {
                float tv = (p == 0) ? tj[j].x : (p == 1) ? tj[j].y : (p == 2) ? tj[j].z : tj[j].w;
                gt[j] = gelu_exact(tv);
            }
            float tv[6];
            #pragma unroll
            for (int i = 0; i < NT; ++i) {
                float s = s_t2b[i];
                #pragma unroll
                for (int j = 0; j < NT; ++j) s += gt[j] * s_t2w[i * 6 + j];
                tv[i] = s;
            }
            float m = tv[0];
            #pragma unroll
            for (int i = 1; i < NT; ++i) m = fmaxf(m, tv[i]);
            float s = 0.f;
            #pragma unroll
            for (int i = 0; i < NT; ++i) { tv[i] = expf(tv[i] - m); s += tv[i]; }
            float inv = 1.f / s;
            #pragma unroll
            for (int i = 0; i < NT; ++i) task[i] = tv[i] * inv;
        }

        // basis = softmax8(fc2(gelu(a[p])))
        float basis[8];
        {
            float g[8];
            #pragma unroll
            for (int j = 0; j < 8; ++j) g[j] = gelu_exact(a[p][j]);
            float bv[8];
            #pragma unroll
            for (int i = 0; i < 8; ++i) {
                float s = s_b2b[i];
                #pragma unroll
                for (int j = 0; j < 8; ++j) s += g[j] * s_b2w[i * 8 + j];
                bv[i] = s;
            }
            float m = bv[0];
            #pragma unroll
            for (int i = 1; i < 8; ++i) m = fmaxf(m, bv[i]);
            float s = 0.f;
            #pragma unroll
            for (int i = 0; i < 8; ++i) { bv[i] = expf(bv[i] - m); s += bv[i]; }
            float inv = 1.f / s;
            #pragma unroll
            for (int i = 0; i < 8; ++i) basis[i] = bv[i] * inv;
        }

        #pragma unroll
        for (int j = 0; j < 6; ++j) {
            uint4 q;
            q.x = pack_bf16(task[j] * basis[0], task[j] * basis[1]);
            q.y = pack_bf16(task[j] * basis[2], task[j] * basis[3]);
            q.z = pack_bf16(task[j] * basis[4], task[j] * basis[5]);
            q.w = pack_bf16(task[j] * basis[6], task[j] * basis[7]);
            c2[(size_t)j * NPIX + pix0 + p] = q;
        }
    }
}

// ---------------- Kernel C: implicit-GEMM 3x3 conv via bf16 MFMA, K=448 ----------------
__global__ __launch_bounds__(256, 3) void conv_kernel(
    const uint4* __restrict__ c2,           // [6][NPIX] 16B chunks
    const unsigned short* __restrict__ WfB, // [14][8][64][8] bf16 fragment-ordered
    float* __restrict__ out)                // [8][128][256][256] f32
{
    __shared__ uint4 tile4[3120];   // [3][130][64ch] bf16, XOR-swizzled (49,920 B)

    int bid = blockIdx.x;
    int s = bid & 1;
    int y = (bid >> 1) & 255;
    int b = bid >> 9;
    int x0 = s << 7;
    int tid = threadIdx.x;

    // zero-fill (covers ch 48..63 padding and image borders)
    #pragma unroll 4
    for (int i = tid; i < 3120; i += 256)
        tile4[i] = make_uint4(0u, 0u, 0u, 0u);
    __syncthreads();

    // stage c halo tile: 3 rows x 6 chunks x 130 cols (col innermost -> coalesced)
    for (int idx = tid; idx < 2340; idx += 256) {
        int dyc = idx / 130;
        int col = idx - dyc * 130;
        int dy  = dyc / 6;
        int ch  = dyc - dy * 6;
        int gy = y + dy - 1;
        int gx = x0 - 1 + col;
        if ((unsigned)gy < 256u && (unsigned)gx < 256u) {
            uint4 v = c2[(size_t)ch * NPIX + (((size_t)b << 16) + (gy << 8) + gx)];
            int lb = ((dy * COLS + col) << 7) + (ch << 4);
            lb ^= (col & 7) << 4;
            tile4[lb >> 4] = v;
        }
    }
    __syncthreads();

    int lane = tid & 63;
    int wv = tid >> 6;
    int wm = wv & 1;
    int wn = wv >> 1;
    int o0 = wm << 6;
    int nbase = wn << 2;          // N-group base (of 16-pixel groups)
    int lrow = lane & 15;         // m (for A/D) and n (for B/D)
    int lk   = lane >> 4;         // k sub-block

    f32x4 acc[4][4];
    #pragma unroll
    for (int mi = 0; mi < 4; ++mi)
        #pragma unroll
        for (int ni = 0; ni < 4; ++ni)
            acc[mi][ni] = (f32x4){0.f, 0.f, 0.f, 0.f};

    const char* tbase = (const char*)tile4;

    #pragma unroll
    for (int ks = 0; ks < KSTEPS; ++ks) {
        bf16x8 a[4];
        #pragma unroll
        for (int mi = 0; mi < 4; ++mi)
            a[mi] = *(const bf16x8*)(WfB + ((size_t)((ks * 8) + wm * 4 + mi) * 64 + lane) * 8);

        // k0 = ks*32 + lk*8 ; tap = k0/48 (clamped), ch = k0 - tap*48
        int k0 = ks * 32 + (lk << 3);
        int tap = k0 / 48;
        if (tap > 8) tap = 8;        // k>=432 pad: lands in zeroed ch48..63 region
        int ch = k0 - tap * 48;
        int dy = tap / 3;
        int dx = tap - dy * 3;

        #pragma unroll
        for (int ni = 0; ni < 4; ++ni) {
            int col = ((nbase + ni) << 4) + lrow + dx;
            int lb = ((dy * COLS + col) << 7) + (ch << 1);
            lb ^= (col & 7) << 4;
            bf16x8 bfr = *(const bf16x8*)(tbase + lb);
            #pragma unroll
            for (int mi = 0; mi < 4; ++mi)
                acc[mi][ni] = __builtin_amdgcn_mfma_f32_16x16x32_bf16(a[mi], bfr, acc[mi][ni], 0, 0, 0);
        }
    }

    // D layout: col = lane&15 (pixel), row = (lane>>4)*4 + r (out channel)
    int orow = lk << 2;
    #pragma unroll
    for (int mi = 0; mi < 4; ++mi) {
        #pragma unroll
        for (int ni = 0; ni < 4; ++ni) {
            int o = o0 + mi * 16 + orow;
            int xx = x0 + ((nbase + ni) << 4) + lrow;
            float* op = out + (((size_t)(b * 128 + o)) << 16) + (y << 8) + xx;
            #pragma unroll
            for (int r = 0; r < 4; ++r)
                op[(size_t)r << 16] = acc[mi][ni][r];
        }
    }
}

extern "C" void kernel_launch(void* const* d_in, const int* in_sizes, int n_in,
                              void* d_out, int out_size, void* d_ws, size_t ws_size,
                              hipStream_t stream) {
    const float* x      = (const float*)d_in[0];
    const float* flux   = (const float*)d_in[1];
    const float* prompt = (const float*)d_in[2];
    const float* conv_w = (const float*)d_in[3];
    const float* b1w    = (const float*)d_in[4];
    const float* b1b    = (const float*)d_in[5];
    const float* b2w    = (const float*)d_in[6];
    const float* b2b    = (const float*)d_in[7];
    const float* t1w    = (const float*)d_in[8];
    const float* t1b    = (const float*)d_in[9];
    const float* t2w    = (const float*)d_in[10];
    const float* t2b    = (const float*)d_in[11];
    float* out = (float*)d_out;

    // ws: c2 50,331,648 B ; WfB 114,688 B ; traw [6][NPIX] f32 = 12,582,912 B
    char* ws = (char*)d_ws;
    uint4* c2 = (uint4*)ws;
    unsigned short* WfB = (unsigned short*)(ws + (size_t)6 * NPIX * 16);
    float* traw = (float*)(ws + (size_t)6 * NPIX * 16 + 131072);

    fold_weights_kernel<<<224, 256, 0, stream>>>(conv_w, prompt, WfB);
    flux_mlp_kernel<<<1024, 128, 0, stream>>>(flux, t1w, t1b, traw);
    basis_epilogue_kernel<<<1024, 128, 0, stream>>>(x, traw, b1w, b1b, b2w, b2b,
                                                    t2w, t2b, c2);
    conv_kernel<<<4096, 256, 0, stream>>>(c2, WfB, out);
}

// Round 14
// 236.563 us; speedup vs baseline: 1.1565x; 1.1565x over previous
//
#include <hip/hip_runtime.h>
#include <hip/hip_bf16.h>
#include <math.h>

#define HW   65536   // 256*256
#define NPIX 524288  // 8*65536
#define NB   8
#define NT   6
#define NC   48      // nt*nb combined channels
#define DIM  64
#define EE   128
#define KSTEPS 14    // K = 9 taps * 48 ch = 432, padded to 448 = 14 * 32
#define KVALID 432
#define COLS 130

typedef short bf16x8 __attribute__((ext_vector_type(8)));
typedef float f32x4  __attribute__((ext_vector_type(4)));

__device__ __forceinline__ float gelu_exact(float v) {
    return 0.5f * v * (1.0f + erff(v * 0.70710678118654752f));
}

__device__ __forceinline__ unsigned pack_bf16(float v0, float v1) {
    __hip_bfloat16 h0 = __float2bfloat16(v0);
    __hip_bfloat16 h1 = __float2bfloat16(v1);
    return (unsigned)(*(unsigned short*)&h0) | ((unsigned)(*(unsigned short*)&h1) << 16);
}

// async global->LDS, 16B per lane; LDS dest wave-uniform, global src per-lane
__device__ __forceinline__ void gload_lds16(const float* g, float* l) {
    __builtin_amdgcn_global_load_lds(
        (const __attribute__((address_space(1))) unsigned int*)g,
        (__attribute__((address_space(3))) unsigned int*)l,
        16, 0, 0);
}

// ---------------- Kernel A: fold prompt into conv weights, fragment-ordered bf16 ----
__global__ __launch_bounds__(256) void fold_weights_kernel(
    const float* __restrict__ conv_w,   // [128][128][3][3]
    const float* __restrict__ prompt,   // [6][8][128]
    unsigned short* __restrict__ WfB)   // [14][8][64][8] bf16
{
    int f = blockIdx.x * 256 + threadIdx.x;   // 0 .. 57343
    int j    = f & 7;
    int lane = (f >> 3) & 63;
    int ob   = (f >> 9) & 7;
    int ks   = f >> 12;

    int o = ob * 16 + (lane & 15);
    int k = ks * 32 + ((lane >> 4) << 3) + j;

    float acc = 0.f;
    if (k < KVALID) {
        int tap = k / 48;
        int tk  = k - tap * 48;
        int dy = tap / 3;
        int dx = tap - dy * 3;
        const float* pw = conv_w + ((size_t)o * EE) * 9 + dy * 3 + dx;
        const float* pp = prompt + (size_t)tk * EE;
        #pragma unroll 4
        for (int e = 0; e < EE; ++e)
            acc += pw[(size_t)e * 9] * pp[e];
    }
    __hip_bfloat16 h = __float2bfloat16(acc);
    WfB[f] = *(unsigned short*)&h;
}

// ---------------- Kernel B: routing via global_load_lds slab pipeline ----
// Block = 256 pixels, 1 px/thread. 12 slices of 16 channels (8 flux + 4 x)
// streamed into double-buffered 16KB LDS slabs via global_load_lds (zero
// VGPR staging cost; one wave-instr = one 1KB channel row). Consume is
// slab[c][tid] (2-way bank alias = free). Live set ~50 VGPR by construction.
__global__ __launch_bounds__(256) void routing_kernel(
    const float* __restrict__ x,      // [8][64][256][256]
    const float* __restrict__ flux,   // [8][128][256][256]
    const float* __restrict__ b1w, const float* __restrict__ b1b,
    const float* __restrict__ b2w, const float* __restrict__ b2b,
    const float* __restrict__ t1w, const float* __restrict__ t1b,
    const float* __restrict__ t2w, const float* __restrict__ t2b,
    uint4* __restrict__ c2)           // [6][NPIX] 16B chunks
{
    __shared__ float slab[2][16][256];   // 2 x 16KB
    __shared__ float s_b1w[DIM * 8];     // [ci][j] transposed
    __shared__ float s_t1w[EE * 8];      // [ci][j] transposed, j<6 padded 0
    __shared__ float s_b2w[64];
    __shared__ float s_t2w[36];
    __shared__ float s_b1b[8], s_b2b[8], s_t1b[8], s_t2b[8];

    int tid = threadIdx.x;
    for (int i = tid; i < DIM * 8; i += 256) {
        int ci = i >> 3, j = i & 7;
        s_b1w[i] = b1w[j * DIM + ci];
    }
    for (int i = tid; i < EE * 8; i += 256) {
        int ci = i >> 3, j = i & 7;
        s_t1w[i] = (j < NT) ? t1w[j * EE + ci] : 0.f;
    }
    if (tid < 64) s_b2w[tid] = b2w[tid];
    if (tid < 36) s_t2w[tid] = t2w[tid];
    if (tid < 8) {
        s_b1b[tid] = b1b[tid];
        s_b2b[tid] = b2b[tid];
        s_t1b[tid] = (tid < NT) ? t1b[tid] : 0.f;
        s_t2b[tid] = (tid < NT) ? t2b[tid] : 0.f;
    }

    int gid = blockIdx.x * 256 + tid;    // this thread's pixel
    int b   = gid >> 16;
    int px0 = (blockIdx.x << 8) & (HW - 1);   // block's pixel base in image

    const float* fbase = flux + (size_t)b * EE * HW + px0;
    const float* xbase = x    + (size_t)b * DIM * HW + px0;

    int wv   = tid >> 6;          // wave id 0..3
    int lane = tid & 63;
    int loff = lane << 2;         // lane's float offset (16B per lane)

    // stage rows wv, wv+4, wv+8, wv+12 of slice s into slab[buf]
    // slice 0..7 = flux ch 16s..16s+15 ; slice 8..11 = x ch 16(s-8)..
    #define STAGE(s, buf)                                                     \
        {                                                                     \
            const float* base_ = ((s) < 8) ? (fbase + ((size_t)((s) << 4) * HW)) \
                                           : (xbase + ((size_t)(((s) - 8) << 4) * HW)); \
            _Pragma("unroll")                                                 \
            for (int r_ = 0; r_ < 4; ++r_) {                                  \
                int row_ = wv + (r_ << 2);                                    \
                gload_lds16(base_ + (size_t)row_ * HW + loff,                 \
                            &slab[buf][row_][0]);                             \
            }                                                                 \
        }

    STAGE(0, 0);
    __syncthreads();   // weights + slice 0 ready

    float t[6], a[8];
    #pragma unroll
    for (int j = 0; j < NT; ++j) t[j] = s_t1b[j];
    #pragma unroll
    for (int j = 0; j < 8; ++j) a[j] = s_b1b[j];

    // ---- flux slices 0..7 ----
    #pragma unroll 1
    for (int s = 0; s < 8; ++s) {
        int buf = s & 1;
        STAGE(s + 1, buf ^ 1);   // s=7 stages slice 8 (x slice 0)
        #pragma unroll
        for (int c = 0; c < 16; ++c) {
            float v = slab[buf][c][tid];
            v = (v == v) ? v : 0.f;
            const float* wp = &s_t1w[((s << 4) + c) * 8];
            float4 wA = *(const float4*)wp;
            float2 wB = *(const float2*)(wp + 4);
            t[0] += v * wA.x;
            t[1] += v * wA.y;
            t[2] += v * wA.z;
            t[3] += v * wA.w;
            t[4] += v * wB.x;
            t[5] += v * wB.y;
        }
        __syncthreads();   // drains stage loads + syncs consumers
    }

    // ---- x slices 8..11 ----
    #pragma unroll 1
    for (int s = 8; s < 12; ++s) {
        int buf = s & 1;
        if (s < 11) STAGE(s + 1, buf ^ 1);
        int c0 = (s - 8) << 4;
        #pragma unroll
        for (int c = 0; c < 16; ++c) {
            float v = slab[buf][c][tid];
            const float* wp = &s_b1w[(c0 + c) * 8];
            float4 wa = *(const float4*)wp;
            float4 wb = *(const float4*)(wp + 4);
            a[0] += v * wa.x;
            a[1] += v * wa.y;
            a[2] += v * wa.z;
            a[3] += v * wa.w;
            a[4] += v * wb.x;
            a[5] += v * wb.y;
            a[6] += v * wb.z;
            a[7] += v * wb.w;
        }
        if (s < 11) __syncthreads();
    }

    #undef STAGE

    // ---- task = softmax6(fc2(gelu(t))) ----
    float task[6];
    {
        float gt[6];
        #pragma unroll
        for (int j = 0; j < NT; ++j) gt[j] = gelu_exact(t[j]);
        float tv[6];
        #pragma unroll
        for (int i = 0; i < NT; ++i) {
            float s = s_t2b[i];
            #pragma unroll
            for (int j = 0; j < NT; ++j) s += gt[j] * s_t2w[i * 6 + j];
            tv[i] = s;
        }
        float m = tv[0];
        #pragma unroll
        for (int i = 1; i < NT; ++i) m = fmaxf(m, tv[i]);
        float s = 0.f;
        #pragma unroll
        for (int i = 0; i < NT; ++i) { tv[i] = expf(tv[i] - m); s += tv[i]; }
        float inv = 1.f / s;
        #pragma unroll
        for (int i = 0; i < NT; ++i) task[i] = tv[i] * inv;
    }

    // ---- basis = softmax8(fc2(gelu(a))) ----
    float basis[8];
    {
        float g[8];
        #pragma unroll
        for (int j = 0; j < 8; ++j) g[j] = gelu_exact(a[j]);
        float bv[8];
        #pragma unroll
        for (int i = 0; i < 8; ++i) {
            float s = s_b2b[i];
            #pragma unroll
            for (int j = 0; j < 8; ++j) s += g[j] * s_b2w[i * 8 + j];
            bv[i] = s;
        }
        float m = bv[0];
        #pragma unroll
        for (int i = 1; i < 8; ++i) m = fmaxf(m, bv[i]);
        float s = 0.f;
        #pragma unroll
        for (int i = 0; i < 8; ++i) { bv[i] = expf(bv[i] - m); s += bv[i]; }
        float inv = 1.f / s;
        #pragma unroll
        for (int i = 0; i < 8; ++i) basis[i] = bv[i] * inv;
    }

    // ---- outer product -> 6 chunk stores, naturally contiguous per wave ----
    #pragma unroll
    for (int j = 0; j < 6; ++j) {
        uint4 q;
        q.x = pack_bf16(task[j] * basis[0], task[j] * basis[1]);
        q.y = pack_bf16(task[j] * basis[2], task[j] * basis[3]);
        q.z = pack_bf16(task[j] * basis[4], task[j] * basis[5]);
        q.w = pack_bf16(task[j] * basis[6], task[j] * basis[7]);
        c2[(size_t)j * NPIX + gid] = q;
    }
}

// ---------------- Kernel C: implicit-GEMM 3x3 conv via bf16 MFMA, K=448 ----------------
__global__ __launch_bounds__(256, 3) void conv_kernel(
    const uint4* __restrict__ c2,           // [6][NPIX] 16B chunks
    const unsigned short* __restrict__ WfB, // [14][8][64][8] bf16 fragment-ordered
    float* __restrict__ out)                // [8][128][256][256] f32
{
    __shared__ uint4 tile4[3120];   // [3][130][64ch] bf16, XOR-swizzled (49,920 B)

    int bid = blockIdx.x;
    int s = bid & 1;
    int y = (bid >> 1) & 255;
    int b = bid >> 9;
    int x0 = s << 7;
    int tid = threadIdx.x;

    // zero-fill (covers ch 48..63 padding and image borders)
    #pragma unroll 4
    for (int i = tid; i < 3120; i += 256)
        tile4[i] = make_uint4(0u, 0u, 0u, 0u);
    __syncthreads();

    // stage c halo tile: 3 rows x 6 chunks x 130 cols (col innermost -> coalesced)
    for (int idx = tid; idx < 2340; idx += 256) {
        int dyc = idx / 130;
        int col = idx - dyc * 130;
        int dy  = dyc / 6;
        int ch  = dyc - dy * 6;
        int gy = y + dy - 1;
        int gx = x0 - 1 + col;
        if ((unsigned)gy < 256u && (unsigned)gx < 256u) {
            uint4 v = c2[(size_t)ch * NPIX + (((size_t)b << 16) + (gy << 8) + gx)];
            int lb = ((dy * COLS + col) << 7) + (ch << 4);
            lb ^= (col & 7) << 4;
            tile4[lb >> 4] = v;
        }
    }
    __syncthreads();

    int lane = tid & 63;
    int wv = tid >> 6;
    int wm = wv & 1;
    int wn = wv >> 1;
    int o0 = wm << 6;
    int nbase = wn << 2;          // N-group base (of 16-pixel groups)
    int lrow = lane & 15;         // m (for A/D) and n (for B/D)
    int lk   = lane >> 4;         // k sub-block

    f32x4 acc[4][4];
    #pragma unroll
    for (int mi = 0; mi < 4; ++mi)
        #pragma unroll
        for (int ni = 0; ni < 4; ++ni)
            acc[mi][ni] = (f32x4){0.f, 0.f, 0.f, 0.f};

    const char* tbase = (const char*)tile4;

    #pragma unroll
    for (int ks = 0; ks < KSTEPS; ++ks) {
        bf16x8 a[4];
        #pragma unroll
        for (int mi = 0; mi < 4; ++mi)
            a[mi] = *(const bf16x8*)(WfB + ((size_t)((ks * 8) + wm * 4 + mi) * 64 + lane) * 8);

        // k0 = ks*32 + lk*8 ; tap = k0/48 (clamped), ch = k0 - tap*48
        int k0 = ks * 32 + (lk << 3);
        int tap = k0 / 48;
        if (tap > 8) tap = 8;        // k>=432 pad: lands in zeroed ch48..63 region
        int ch = k0 - tap * 48;
        int dy = tap / 3;
        int dx = tap - dy * 3;

        #pragma unroll
        for (int ni = 0; ni < 4; ++ni) {
            int col = ((nbase + ni) << 4) + lrow + dx;
            int lb = ((dy * COLS + col) << 7) + (ch << 1);
            lb ^= (col & 7) << 4;
            bf16x8 bfr = *(const bf16x8*)(tbase + lb);
            #pragma unroll
            for (int mi = 0; mi < 4; ++mi)
                acc[mi][ni] = __builtin_amdgcn_mfma_f32_16x16x32_bf16(a[mi], bfr, acc[mi][ni], 0, 0, 0);
        }
    }

    // D layout: col = lane&15 (pixel), row = (lane>>4)*4 + r (out channel)
    int orow = lk << 2;
    #pragma unroll
    for (int mi = 0; mi < 4; ++mi) {
        #pragma unroll
        for (int ni = 0; ni < 4; ++ni) {
            int o = o0 + mi * 16 + orow;
            int xx = x0 + ((nbase + ni) << 4) + lrow;
            float* op = out + (((size_t)(b * 128 + o)) << 16) + (y << 8) + xx;
            #pragma unroll
            for (int r = 0; r < 4; ++r)
                op[(size_t)r << 16] = acc[mi][ni][r];
        }
    }
}

extern "C" void kernel_launch(void* const* d_in, const int* in_sizes, int n_in,
                              void* d_out, int out_size, void* d_ws, size_t ws_size,
                              hipStream_t stream) {
    const float* x      = (const float*)d_in[0];
    const float* flux   = (const float*)d_in[1];
    const float* prompt = (const float*)d_in[2];
    const float* conv_w = (const float*)d_in[3];
    const float* b1w    = (const float*)d_in[4];
    const float* b1b    = (const float*)d_in[5];
    const float* b2w    = (const float*)d_in[6];
    const float* b2b    = (const float*)d_in[7];
    const float* t1w    = (const float*)d_in[8];
    const float* t1b    = (const float*)d_in[9];
    const float* t2w    = (const float*)d_in[10];
    const float* t2b    = (const float*)d_in[11];
    float* out = (float*)d_out;

    // ws: c2 [6][524288] uint4 = 50,331,648 B ; WfB [14][8][64][8] bf16 = 114,688 B
    char* ws = (char*)d_ws;
    uint4* c2 = (uint4*)ws;
    unsigned short* WfB = (unsigned short*)(ws + (size_t)6 * NPIX * 16);

    fold_weights_kernel<<<224, 256, 0, stream>>>(conv_w, prompt, WfB);
    routing_kernel<<<2048, 256, 0, stream>>>(x, flux, b1w, b1b, b2w, b2b,
                                             t1w, t1b, t2w, t2b, c2);
    conv_kernel<<<4096, 256, 0, stream>>>(c2, WfB, out);
}